// Round 6
// baseline (962.060 us; speedup 1.0000x reference)
//
#include <hip/hip_runtime.h>
#include <hip/hip_bf16.h>
#include <cstddef>
#include <cstdint>

#define NM 50000
#define NA 50000
#define ND 500
#define FEAT 128
#define KDIM 768
#define BATCH 1024
#define NEDGE 1600000
#define NNODES 100000
#define NPARTS 391   // ceil(100000/256)

#define REC (2 * NEDGE)               // 3,200,000 records
#define BSHIFT 14
#define BSIZE (1 << BSHIFT)           // 16384 slots per bucket (64KB adj window)
#define NB ((REC + BSIZE - 1) >> BSHIFT)  // 196 buckets
#define FILLA_BLOCKS 800
#define FILLA_EPB (NEDGE / FILLA_BLOCKS)  // 2000 edges per block (exact)
#define FILLB_SPLIT 4

typedef __bf16 bf16_t;
typedef bf16_t bf16x8 __attribute__((ext_vector_type(8)));
typedef bf16_t bf16x2 __attribute__((ext_vector_type(2)));
typedef float f32x4 __attribute__((ext_vector_type(4)));

__device__ __forceinline__ float sigf(float x) { return 1.0f / (1.0f + __expf(-x)); }

// ---------------- W[768,128] fp32 -> Wt[128,768] bf16 ----------------
__global__ __launch_bounds__(256) void wconv_kernel(const float* __restrict__ W,
                                                    bf16_t* __restrict__ Wt)
{
  int c = blockIdx.x;
  for (int k = threadIdx.x; k < KDIM; k += 256)
    Wt[(size_t)c * KDIM + k] = (bf16_t)W[(size_t)k * FEAT + c];
}

// ---------------- projection via MFMA: C = sigmoid(A[M,768] @ W[768,128] + b) ----
// Optional per-row scale (pre-scale by dinv), optional C2 = 0.25*sigmoid (fp32).
template<bool BF16OUT>
__global__ __launch_bounds__(256) void proj_mfma(
    const float* __restrict__ A, const bf16_t* __restrict__ Wt,
    const float* __restrict__ bias, void* __restrict__ Cout, int M,
    const float* __restrict__ rowscale, int scaleBase,
    float* __restrict__ C2)
{
  __shared__ bf16x8 sm[1024];  // [0..511]=A frags, [512..1023]=B frags
  const int tid = threadIdx.x;
  const int rowBase = blockIdx.x * 128;
  const int lane = tid & 63;
  const int wid = tid >> 6;

  f32x4 acc[4][4];
  #pragma unroll
  for (int m = 0; m < 4; ++m)
    #pragma unroll
    for (int n = 0; n < 4; ++n)
      acc[m][n] = (f32x4){0.f, 0.f, 0.f, 0.f};

  const int rl0 = ((tid >> 6) << 4) + (tid & 15);
  const int k8 = (tid >> 4) & 3;

  for (int k0 = 0; k0 < KDIM; k0 += 32) {
    #pragma unroll
    for (int i = 0; i < 2; ++i) {
      int rloc = rl0 + 64 * i;
      int rg = rowBase + rloc;
      if (rg > M - 1) rg = M - 1;
      const float* ap = A + (size_t)rg * KDIM + k0 + k8 * 8;
      float4 v0 = *(const float4*)ap;
      float4 v1 = *(const float4*)(ap + 4);
      bf16x8 w;
      w[0] = (bf16_t)v0.x; w[1] = (bf16_t)v0.y; w[2] = (bf16_t)v0.z; w[3] = (bf16_t)v0.w;
      w[4] = (bf16_t)v1.x; w[5] = (bf16_t)v1.y; w[6] = (bf16_t)v1.z; w[7] = (bf16_t)v1.w;
      sm[tid + i * 256] = w;
      sm[512 + tid + i * 256] = *(const bf16x8*)(Wt + (size_t)rloc * KDIM + k0 + k8 * 8);
    }
    __syncthreads();
    bf16x8 a[4], b[4];
    const int fm = (wid >> 1) * 4, fn = (wid & 1) * 4;
    #pragma unroll
    for (int m = 0; m < 4; ++m) a[m] = sm[(fm + m) * 64 + lane];
    #pragma unroll
    for (int n = 0; n < 4; ++n) b[n] = sm[512 + (fn + n) * 64 + lane];
    #pragma unroll
    for (int m = 0; m < 4; ++m)
      #pragma unroll
      for (int n = 0; n < 4; ++n)
        acc[m][n] = __builtin_amdgcn_mfma_f32_16x16x32_bf16(a[m], b[n], acc[m][n], 0, 0, 0);
    __syncthreads();
  }

  // C frag layout: col=lane&15, row=(lane>>4)*4+reg
  const int wRow = (wid >> 1) * 64, wCol = (wid & 1) * 64;
  const int r0 = (lane >> 4) * 4, cc = lane & 15;
  #pragma unroll
  for (int n = 0; n < 4; ++n) {
    int col = wCol + n * 16 + cc;
    float bb = bias[col];
    #pragma unroll
    for (int m = 0; m < 4; ++m) {
      #pragma unroll
      for (int r = 0; r < 4; ++r) {
        int row = rowBase + wRow + m * 16 + r0 + r;
        if (row < M) {
          float v = sigf(acc[m][n][r] + bb);
          float sc = rowscale ? rowscale[scaleBase + row] : 1.0f;
          if constexpr (BF16OUT)
            ((bf16_t*)Cout)[(size_t)row * FEAT + col] = (bf16_t)(v * sc);
          else
            ((float*)Cout)[(size_t)row * FEAT + col] = v * sc;
          if (C2) C2[(size_t)row * FEAT + col] = 0.25f * v;
        }
      }
    }
  }
}

// ---------------- attention ----------------
__global__ __launch_bounds__(256) void attn_kernel(
    const float* __restrict__ vmi, const float* __restrict__ vkey,
    const float* __restrict__ vval, bf16_t* __restrict__ zm)
{
  const int i = blockIdx.x;
  const int tid = threadIdx.x;
  __shared__ float vs[FEAT];
  __shared__ float al[ND];
  __shared__ float red[4];
  __shared__ float totS;
  if (tid < FEAT) vs[tid] = vmi[(size_t)i * FEAT + tid];
  __syncthreads();
  float part = 0.f;
  for (int j = tid; j < ND; j += 256) {
    const float* kr = vkey + (size_t)j * FEAT;
    float dot = 0.f;
    #pragma unroll 8
    for (int k = 0; k < FEAT; k += 4) {
      float4 kv = *(const float4*)(kr + k);
      dot += vs[k] * kv.x + vs[k + 1] * kv.y + vs[k + 2] * kv.z + vs[k + 3] * kv.w;
    }
    al[j] = dot;
    part += dot;
  }
  #pragma unroll
  for (int o = 32; o > 0; o >>= 1) part += __shfl_down(part, o, 64);
  if ((tid & 63) == 0) red[tid >> 6] = part;
  __syncthreads();
  if (tid == 0) totS = red[0] + red[1] + red[2] + red[3];
  __syncthreads();
  const float inv = 1.0f / totS;
  if (tid < FEAT) {
    float s = 0.f;
    #pragma unroll 4
    for (int j = 0; j < ND; ++j) s += al[j] * vval[(size_t)j * FEAT + tid];
    float z = 0.5f * (s * inv + vs[tid]);
    zm[(size_t)i * FEAT + tid] = (bf16_t)z;
  }
}

// ---------------- degree histogram (nt edge reads) ----------------
__global__ void hist_kernel(const int* __restrict__ src, const int* __restrict__ dst,
                            int* __restrict__ deg)
{
  int stride = gridDim.x * blockDim.x;
  for (int e = blockIdx.x * blockDim.x + threadIdx.x; e < NEDGE; e += stride) {
    int s = __builtin_nontemporal_load(&src[e]);
    int d = __builtin_nontemporal_load(&dst[e]);
    atomicAdd(&deg[s], 1);
    atomicAdd(&deg[NM + d], 1);
  }
}

// ---------------- scan step A ----------------
__global__ __launch_bounds__(256) void scan_blocksum(const int* __restrict__ deg,
                                                     int* __restrict__ parts)
{
  int i = blockIdx.x * 256 + threadIdx.x;
  int v = (i < NNODES) ? deg[i] : 0;
  __shared__ int red[4];
  #pragma unroll
  for (int o = 32; o > 0; o >>= 1) v += __shfl_down(v, o, 64);
  if ((threadIdx.x & 63) == 0) red[threadIdx.x >> 6] = v;
  __syncthreads();
  if (threadIdx.x == 0) parts[blockIdx.x] = red[0] + red[1] + red[2] + red[3];
}

// ---------------- scan step B ----------------
__global__ __launch_bounds__(512) void scan_parts(int* __restrict__ parts)
{
  __shared__ int s[512];
  int t = threadIdx.x;
  int v = (t < NPARTS) ? parts[t] : 0;
  s[t] = v;
  __syncthreads();
  for (int o = 1; o < 512; o <<= 1) {
    int x = (t >= o) ? s[t - o] : 0;
    __syncthreads();
    s[t] += x;
    __syncthreads();
  }
  if (t < NPARTS) parts[t] = s[t] - v;  // exclusive
}

// ---------------- scan step C ----------------
__global__ __launch_bounds__(256) void scan_final(const int* __restrict__ deg,
                                                  const int* __restrict__ parts,
                                                  int* __restrict__ offs,
                                                  int* __restrict__ curs,
                                                  float* __restrict__ dinv)
{
  __shared__ int s[256];
  int t = threadIdx.x;
  int i = blockIdx.x * 256 + t;
  int v = (i < NNODES) ? deg[i] : 0;
  s[t] = v;
  __syncthreads();
  for (int o = 1; o < 256; o <<= 1) {
    int x = (t >= o) ? s[t - o] : 0;
    __syncthreads();
    s[t] += x;
    __syncthreads();
  }
  if (i < NNODES) {
    int off = parts[blockIdx.x] + s[t] - v;
    offs[i] = off;
    curs[i] = off;
    dinv[i] = (v > 0) ? rsqrtf((float)v) : 0.f;
  }
  if (i == 0) offs[NNODES] = 2 * NEDGE;
}

// ---------------- fill pass A: edges -> slot-bucketed records ----------------
// One scan of edges. Record = (slot<<32 | neighbor), bucket = slot>>14 (exact
// capacity 16384/bucket). Records staged in LDS, emitted in per-(block,bucket)
// reserved runs (~160B sequential) -> near-clean record writes.
__global__ __launch_bounds__(256) void fill_recA(
    const int* __restrict__ src, const int* __restrict__ dst,
    int* __restrict__ curs, int* __restrict__ bcur,
    unsigned long long* __restrict__ rec)
{
  __shared__ unsigned long long recL[2 * FILLA_EPB];  // 32 KB
  __shared__ int bhist[NB];
  __shared__ int bbase[NB];
  const int tid = threadIdx.x;
  for (int b = tid; b < NB; b += 256) bhist[b] = 0;
  __syncthreads();
  const int e0 = blockIdx.x * FILLA_EPB;
  for (int i = tid; i < FILLA_EPB; i += 256) {
    int s = __builtin_nontemporal_load(&src[e0 + i]);
    int d = __builtin_nontemporal_load(&dst[e0 + i]);
    int slot1 = atomicAdd(&curs[s], 1);        // mashup list entry: neighbor d
    int slot2 = atomicAdd(&curs[NM + d], 1);   // api list entry: neighbor s
    recL[2 * i]     = ((unsigned long long)(unsigned)slot1 << 32) | (unsigned)d;
    recL[2 * i + 1] = ((unsigned long long)(unsigned)slot2 << 32) | (unsigned)s;
    atomicAdd(&bhist[slot1 >> BSHIFT], 1);
    atomicAdd(&bhist[slot2 >> BSHIFT], 1);
  }
  __syncthreads();
  for (int b = tid; b < NB; b += 256) {
    int c = bhist[b];
    bbase[b] = c ? atomicAdd(&bcur[b], c) : 0;
    bhist[b] = 0;  // reuse as emit cursor
  }
  __syncthreads();
  for (int i = tid; i < 2 * FILLA_EPB; i += 256) {
    unsigned long long r = recL[i];
    int b = (int)(r >> (32 + BSHIFT));
    int off = atomicAdd(&bhist[b], 1);
    rec[((size_t)b << BSHIFT) + (size_t)(bbase[b] + off)] = r;
  }
}

// ---------------- fill pass B: records -> adj (line-local scatter) ------------
// Block owns 1/4 of one bucket; its adj window is a private 64KB range, so every
// adj line is written by one block only and fills completely before eviction.
__global__ __launch_bounds__(256) void fill_recB(
    const unsigned long long* __restrict__ rec, const int* __restrict__ bcur,
    int* __restrict__ adj)
{
  const int b = blockIdx.x / FILLB_SPLIT;
  const int sub = blockIdx.x % FILLB_SPLIT;
  const int cnt = bcur[b];
  const int lo = sub * (BSIZE / FILLB_SPLIT);
  int hi = lo + (BSIZE / FILLB_SPLIT);
  if (hi > cnt) hi = cnt;
  const unsigned long long* rb = rec + ((size_t)b << BSHIFT);
  for (int i = lo + threadIdx.x; i < hi; i += 256) {
    unsigned long long r = __builtin_nontemporal_load(&rb[i]);
    adj[(int)(r >> 32)] = (int)(r & 0xffffffffu);
  }
}

// ---------------- row-gather helper: sum bf16 rows (one dword per lane) -------
__device__ __forceinline__ void gather8(const uint32_t* __restrict__ base,
                                        const int* __restrict__ adj,
                                        int p, int p1, float& ax, float& ay)
{
  float lax = 0.f, lay = 0.f;
  while (p + 8 <= p1) {
    int u[8];
    #pragma unroll
    for (int j = 0; j < 8; ++j) u[j] = __builtin_nontemporal_load(&adj[p + j]);
    uint32_t w[8];
    #pragma unroll
    for (int j = 0; j < 8; ++j) w[j] = base[(size_t)u[j] * 64];
    #pragma unroll
    for (int j = 0; j < 8; ++j) {
      lax += __uint_as_float(w[j] << 16);
      lay += __uint_as_float(w[j] & 0xffff0000u);
    }
    p += 8;
  }
  while (p < p1) {
    int u = adj[p];
    uint32_t w = base[(size_t)u * 64];
    lax += __uint_as_float(w << 16);
    lay += __uint_as_float(w & 0xffff0000u);
    ++p;
  }
  ax = lax; ay = lay;
}

// ---- pass1 (api side): y01a = y0a + dinv^2 * sum_{m in N(a)} M0y[m] ----------
__global__ __launch_bounds__(256) void prop_pass1(
    const bf16_t* __restrict__ M0y, const bf16_t* __restrict__ y0a,
    bf16_t* __restrict__ y01a,
    const int* __restrict__ offs, const int* __restrict__ adj,
    const float* __restrict__ dinv)
{
  const int a = blockIdx.x * 4 + (threadIdx.x >> 6);
  const int v = NM + a;
  const int lane = threadIdx.x & 63;
  float ax, ay;
  gather8((const uint32_t*)M0y + lane, adj, offs[v], offs[v + 1], ax, ay);
  const float d = dinv[v];
  const float s2 = d * d;
  uint32_t y0 = ((const uint32_t*)y0a)[(size_t)a * 64 + lane];
  bf16x2 pk;
  pk[0] = (bf16_t)(__uint_as_float(y0 << 16) + s2 * ax);
  pk[1] = (bf16_t)(__uint_as_float(y0 & 0xffff0000u) + s2 * ay);
  *(bf16x2*)(y01a + (size_t)a * FEAT + 2 * lane) = pk;
}

// ---- pass2 (mashup side): Sy = M0y + dinv^2 * sum_{a in N(m)} y01a[a] --------
__global__ __launch_bounds__(256) void prop_pass2(
    const bf16_t* __restrict__ y01a, const bf16_t* __restrict__ M0y,
    bf16_t* __restrict__ Sy,
    const int* __restrict__ offs, const int* __restrict__ adj,
    const float* __restrict__ dinv)
{
  const int m = blockIdx.x * 4 + (threadIdx.x >> 6);
  const int lane = threadIdx.x & 63;
  float ax, ay;
  gather8((const uint32_t*)y01a + lane, adj, offs[m], offs[m + 1], ax, ay);
  const float d = dinv[m];
  const float s2 = d * d;
  uint32_t m0 = ((const uint32_t*)M0y)[(size_t)m * 64 + lane];
  bf16x2 pk;
  pk[0] = (bf16_t)(__uint_as_float(m0 << 16) + s2 * ax);
  pk[1] = (bf16_t)(__uint_as_float(m0 & 0xffff0000u) + s2 * ay);
  *(bf16x2*)(Sy + (size_t)m * FEAT + 2 * lane) = pk;
}

// ---- pass3 (api side): O = 0.25*A0 + 0.25*dinv * sum_{m in N(a)} Sy[m] -------
__global__ __launch_bounds__(256) void prop_pass3(
    const bf16_t* __restrict__ Sy, const float* __restrict__ outA,
    bf16_t* __restrict__ Obf,
    const int* __restrict__ offs, const int* __restrict__ adj,
    const float* __restrict__ dinv)
{
  const int a = blockIdx.x * 4 + (threadIdx.x >> 6);
  const int v = NM + a;
  const int lane = threadIdx.x & 63;
  float ax, ay;
  gather8((const uint32_t*)Sy + lane, adj, offs[v], offs[v + 1], ax, ay);
  const float q = 0.25f * dinv[v];
  const float2 prev = *(const float2*)(outA + (size_t)a * FEAT + 2 * lane);
  bf16x2 pk;
  pk[0] = (bf16_t)(prev.x + q * ax);
  pk[1] = (bf16_t)(prev.y + q * ay);
  *(bf16x2*)(Obf + (size_t)a * FEAT + 2 * lane) = pk;
}

// ---------------- pred = Z[1024,128] @ O[50000,128]^T, bf16 MFMA ----------------
__global__ __launch_bounds__(256) void pred_mfma(
    const bf16_t* __restrict__ Z, const bf16_t* __restrict__ O,
    float* __restrict__ out)
{
  const int lane = threadIdx.x & 63;
  const int wid = threadIdx.x >> 6;
  const int nBase = blockIdx.x * 256 + wid * 64;
  const int cc = lane & 15;
  const int kOff = (lane >> 4) * 8;

  bf16x8 b[4][4];
  #pragma unroll
  for (int n = 0; n < 4; ++n) {
    int c = nBase + n * 16 + cc;
    if (c > NA - 1) c = NA - 1;
    #pragma unroll
    for (int kk = 0; kk < 4; ++kk)
      b[n][kk] = *(const bf16x8*)(O + (size_t)c * FEAT + kk * 32 + kOff);
  }

  const int r0 = (lane >> 4) * 4;
  #pragma unroll
  for (int it = 0; it < 4; ++it) {
    const int iBase = blockIdx.y * 256 + it * 64;
    f32x4 acc[4][4];
    #pragma unroll
    for (int m = 0; m < 4; ++m)
      #pragma unroll
      for (int n = 0; n < 4; ++n)
        acc[m][n] = (f32x4){0.f, 0.f, 0.f, 0.f};

    #pragma unroll
    for (int kk = 0; kk < 4; ++kk) {
      bf16x8 a[4];
      #pragma unroll
      for (int m = 0; m < 4; ++m)
        a[m] = *(const bf16x8*)(Z + (size_t)(iBase + cc + m * 16) * FEAT + kk * 32 + kOff);
      #pragma unroll
      for (int m = 0; m < 4; ++m)
        #pragma unroll
        for (int n = 0; n < 4; ++n)
          acc[m][n] = __builtin_amdgcn_mfma_f32_16x16x32_bf16(a[m], b[n][kk], acc[m][n], 0, 0, 0);
    }

    #pragma unroll
    for (int n = 0; n < 4; ++n) {
      int col = nBase + n * 16 + cc;
      if (col < NA) {
        #pragma unroll
        for (int m = 0; m < 4; ++m) {
          #pragma unroll
          for (int r = 0; r < 4; ++r) {
            int row = iBase + m * 16 + r0 + r;
            __builtin_nontemporal_store(acc[m][n][r], &out[(size_t)row * NA + col]);
          }
        }
      }
    }
  }
}

static inline char* alignup(char* p, size_t a) {
  return (char*)(((uintptr_t)p + a - 1) & ~(uintptr_t)(a - 1));
}

extern "C" void kernel_launch(void* const* d_in, const int* in_sizes, int n_in,
                              void* d_out, int out_size, void* d_ws, size_t ws_size,
                              hipStream_t stream) {
  const float* x      = (const float*)d_in[0];
  const float* mashup = (const float*)d_in[1];
  const float* domain = (const float*)d_in[2];
  const float* api    = (const float*)d_in[3];
  const float* Wsde   = (const float*)d_in[4];
  const float* bsde   = (const float*)d_in[5];
  const float* Wval   = (const float*)d_in[6];
  const float* bval   = (const float*)d_in[7];
  const float* Wkey   = (const float*)d_in[8];
  const float* bkey   = (const float*)d_in[9];
  const float* Wsie   = (const float*)d_in[10];
  const float* bsie   = (const float*)d_in[11];
  const int* esrc     = (const int*)d_in[12];
  const int* edst     = (const int*)d_in[13];
  float* out = (float*)d_out;

  // workspace layout
  char* p = (char*)d_ws;
  bf16_t* M0y  = (bf16_t*)p; p += (size_t)NM * FEAT * 2;          // 12.8MB
  bf16_t* y0a  = (bf16_t*)p; p += (size_t)NA * FEAT * 2;          // 12.8MB
  bf16_t* y01a = (bf16_t*)p; p += (size_t)NA * FEAT * 2;          // 12.8MB
  bf16_t* Sy   = (bf16_t*)p; p += (size_t)NM * FEAT * 2;          // 12.8MB
  float*  outA = (float*)p;  p += (size_t)NA * FEAT * 4;          // 25.6MB
  bf16_t* Obf  = (bf16_t*)p; p += (size_t)NA * FEAT * 2;          // 12.8MB
  float*  vmi  = (float*)p;  p += (size_t)BATCH * FEAT * 4;
  float*  vkey = (float*)p;  p += (size_t)ND * FEAT * 4;
  float*  vval = (float*)p;  p += (size_t)ND * FEAT * 4;
  bf16_t* zm   = (bf16_t*)p; p += (size_t)BATCH * FEAT * 2;
  float*  dinv = (float*)p;  p += (size_t)NNODES * 4;
  int* deg  = (int*)p; p += (size_t)NNODES * 4;
  int* offs = (int*)p; p += (size_t)(NNODES + 4) * 4;
  int* curs = (int*)p; p += (size_t)NNODES * 4;
  int* adj  = (int*)p; p += (size_t)2 * NEDGE * 4;                // 12.8MB
  int* parts = (int*)p; p += 512 * 4;
  int* bcur  = (int*)p; p += 256 * 4;
  p = alignup(p, 16);
  bf16_t* wt0 = (bf16_t*)p; p += (size_t)FEAT * KDIM * 2;
  bf16_t* wt1 = (bf16_t*)p; p += (size_t)FEAT * KDIM * 2;
  bf16_t* wt2 = (bf16_t*)p; p += (size_t)FEAT * KDIM * 2;
  bf16_t* wt3 = (bf16_t*)p; p += (size_t)FEAT * KDIM * 2;
  // rec (25.7MB) overlays outA+Obf (38.4MB): dead before projections write outA.
  unsigned long long* rec = (unsigned long long*)outA;

  hipMemsetAsync(deg, 0, NNODES * sizeof(int), stream);
  hipMemsetAsync(bcur, 0, 256 * sizeof(int), stream);

  // ---- graph build first (dinv needed by projection epilogues) ----
  hist_kernel<<<2048, 256, 0, stream>>>(esrc, edst, deg);
  scan_blocksum<<<NPARTS, 256, 0, stream>>>(deg, parts);
  scan_parts<<<1, 512, 0, stream>>>(parts);
  scan_final<<<NPARTS, 256, 0, stream>>>(deg, parts, offs, curs, dinv);
  fill_recA<<<FILLA_BLOCKS, 256, 0, stream>>>(esrc, edst, curs, bcur, rec);
  fill_recB<<<NB * FILLB_SPLIT, 256, 0, stream>>>(rec, bcur, adj);

  // ---- weights + projections ----
  wconv_kernel<<<FEAT, 256, 0, stream>>>(Wsde, wt0);
  wconv_kernel<<<FEAT, 256, 0, stream>>>(Wkey, wt1);
  wconv_kernel<<<FEAT, 256, 0, stream>>>(Wval, wt2);
  wconv_kernel<<<FEAT, 256, 0, stream>>>(Wsie, wt3);

  proj_mfma<false><<<(BATCH + 127) / 128, 256, 0, stream>>>(x, wt0, bsde, vmi, BATCH,
                                                            nullptr, 0, nullptr);
  proj_mfma<false><<<(ND + 127) / 128, 256, 0, stream>>>(domain, wt1, bkey, vkey, ND,
                                                         nullptr, 0, nullptr);
  proj_mfma<false><<<(ND + 127) / 128, 256, 0, stream>>>(domain, wt2, bval, vval, ND,
                                                         nullptr, 0, nullptr);
  attn_kernel<<<BATCH, 256, 0, stream>>>(vmi, vkey, vval, zm);

  // mashup: M0y = dinv[m] * sigmoid(...)   (pre-scaled, bf16)
  proj_mfma<true><<<(NM + 127) / 128, 256, 0, stream>>>(mashup, wt0, bsde, M0y, NM,
                                                        dinv, 0, nullptr);
  // api: y0a = dinv[NM+a] * sigmoid(...), outA = 0.25 * sigmoid(...)
  proj_mfma<true><<<(NA + 127) / 128, 256, 0, stream>>>(api, wt3, bsie, y0a, NA,
                                                        dinv, NM, outA);

  // ---- bipartite LightGCN: out_api = 0.25*(A0 + P^T(M0+M1+M2)) ----
  prop_pass1<<<NA / 4, 256, 0, stream>>>(M0y, y0a, y01a, offs, adj, dinv);
  prop_pass2<<<NM / 4, 256, 0, stream>>>(y01a, M0y, Sy, offs, adj, dinv);
  prop_pass3<<<NA / 4, 256, 0, stream>>>(Sy, outA, Obf, offs, adj, dinv);

  pred_mfma<<<dim3((NA + 255) / 256, BATCH / 256), 256, 0, stream>>>(zm, Obf, out);
}

// Round 7
// 618.894 us; speedup vs baseline: 1.5545x; 1.5545x over previous
//
#include <hip/hip_runtime.h>
#include <hip/hip_bf16.h>
#include <cstddef>
#include <cstdint>

#define NM 50000
#define NA 50000
#define ND 500
#define FEAT 128
#define KDIM 768
#define BATCH 1024
#define NEDGE 1600000
#define MD 128            // ELL row capacity (deg ~ Poisson(32); P(>128) ~ 1e-38)

typedef __bf16 bf16_t;
typedef bf16_t bf16x8 __attribute__((ext_vector_type(8)));
typedef bf16_t bf16x2 __attribute__((ext_vector_type(2)));
typedef float f32x4 __attribute__((ext_vector_type(4)));
typedef unsigned short u16;

__device__ __forceinline__ float sigf(float x) { return 1.0f / (1.0f + __expf(-x)); }

// ---------------- ELL fill with rank trick, XCD node-partitioned --------------
// cnt_m/cnt_a zeroed on entry; atomicAdd returns rank -> direct ELL scatter.
// blockIdx&7 ~ XCD owns 1/8 node range (write-local); 256 groups scan edges.
__global__ __launch_bounds__(256) void fill_ell(
    const int* __restrict__ src, const int* __restrict__ dst,
    int* __restrict__ cnt_m, int* __restrict__ cnt_a,
    u16* __restrict__ adjm, u16* __restrict__ adja)
{
  const int x = blockIdx.x & 7;
  const int grp = blockIdx.x >> 3;            // 0..255
  const int mlo = x * (NM / 8), mhi = mlo + (NM / 8);
  const int alo = x * (NA / 8), ahi = alo + (NA / 8);
  const int ebase = grp * (NEDGE / 256);
  const int eend = ebase + (NEDGE / 256);
  for (int e = ebase + threadIdx.x; e < eend; e += 256) {
    int s = __builtin_nontemporal_load(&src[e]);
    int d = __builtin_nontemporal_load(&dst[e]);
    if (s >= mlo && s < mhi) {
      int r = atomicAdd(&cnt_m[s], 1);
      if (r < MD) adjm[(size_t)s * MD + r] = (u16)d;
    }
    if (d >= alo && d < ahi) {
      int r = atomicAdd(&cnt_a[d], 1);
      if (r < MD) adja[(size_t)d * MD + r] = (u16)s;
    }
  }
}

// ---------------- util: 4x weight transpose->bf16 + deg->dinv ----------------
__global__ __launch_bounds__(256) void util_kernel(
    const float* __restrict__ W0, const float* __restrict__ W1,
    const float* __restrict__ W2, const float* __restrict__ W3,
    bf16_t* __restrict__ T0, bf16_t* __restrict__ T1,
    bf16_t* __restrict__ T2, bf16_t* __restrict__ T3,
    const int* __restrict__ cnt_m, const int* __restrict__ cnt_a,
    float* __restrict__ dm, float* __restrict__ da)
{
  const int b = blockIdx.x;
  if (b < 512) {
    const float* W = (b < 128) ? W0 : (b < 256) ? W1 : (b < 384) ? W2 : W3;
    bf16_t* T      = (b < 128) ? T0 : (b < 256) ? T1 : (b < 384) ? T2 : T3;
    int c = b & 127;
    for (int k = threadIdx.x; k < KDIM; k += 256)
      T[(size_t)c * KDIM + k] = (bf16_t)W[(size_t)k * FEAT + c];
  } else {
    int i = (b - 512) * 256 + threadIdx.x;
    if (i < NM) { int c = cnt_m[i]; dm[i] = c > 0 ? rsqrtf((float)c) : 0.f; }
    if (i < NA) { int c = cnt_a[i]; da[i] = c > 0 ? rsqrtf((float)c) : 0.f; }
  }
}

// ---------------- projection body: C = sigmoid(A[M,768] @ W + b) -------------
template<bool BF16OUT>
__device__ __forceinline__ void proj_body(
    const float* __restrict__ A, const bf16_t* __restrict__ Wt,
    const float* __restrict__ bias, void* __restrict__ Cout, int M, int rowBase,
    const float* __restrict__ rowscale, float* __restrict__ C2)
{
  __shared__ bf16x8 sm[1024];  // [0..511]=A frags, [512..1023]=B frags
  const int tid = threadIdx.x;
  const int lane = tid & 63;
  const int wid = tid >> 6;

  f32x4 acc[4][4];
  #pragma unroll
  for (int m = 0; m < 4; ++m)
    #pragma unroll
    for (int n = 0; n < 4; ++n)
      acc[m][n] = (f32x4){0.f, 0.f, 0.f, 0.f};

  const int rl0 = ((tid >> 6) << 4) + (tid & 15);
  const int k8 = (tid >> 4) & 3;

  for (int k0 = 0; k0 < KDIM; k0 += 32) {
    #pragma unroll
    for (int i = 0; i < 2; ++i) {
      int rloc = rl0 + 64 * i;
      int rg = rowBase + rloc;
      if (rg > M - 1) rg = M - 1;
      const float* ap = A + (size_t)rg * KDIM + k0 + k8 * 8;
      float4 v0 = *(const float4*)ap;
      float4 v1 = *(const float4*)(ap + 4);
      bf16x8 w;
      w[0] = (bf16_t)v0.x; w[1] = (bf16_t)v0.y; w[2] = (bf16_t)v0.z; w[3] = (bf16_t)v0.w;
      w[4] = (bf16_t)v1.x; w[5] = (bf16_t)v1.y; w[6] = (bf16_t)v1.z; w[7] = (bf16_t)v1.w;
      sm[tid + i * 256] = w;
      sm[512 + tid + i * 256] = *(const bf16x8*)(Wt + (size_t)rloc * KDIM + k0 + k8 * 8);
    }
    __syncthreads();
    bf16x8 a[4], b[4];
    const int fm = (wid >> 1) * 4, fn = (wid & 1) * 4;
    #pragma unroll
    for (int m = 0; m < 4; ++m) a[m] = sm[(fm + m) * 64 + lane];
    #pragma unroll
    for (int n = 0; n < 4; ++n) b[n] = sm[512 + (fn + n) * 64 + lane];
    #pragma unroll
    for (int m = 0; m < 4; ++m)
      #pragma unroll
      for (int n = 0; n < 4; ++n)
        acc[m][n] = __builtin_amdgcn_mfma_f32_16x16x32_bf16(a[m], b[n], acc[m][n], 0, 0, 0);
    __syncthreads();
  }

  // C frag layout: col=lane&15, row=(lane>>4)*4+reg
  const int wRow = (wid >> 1) * 64, wCol = (wid & 1) * 64;
  const int r0 = (lane >> 4) * 4, cc = lane & 15;
  #pragma unroll
  for (int n = 0; n < 4; ++n) {
    int col = wCol + n * 16 + cc;
    float bb = bias[col];
    #pragma unroll
    for (int m = 0; m < 4; ++m) {
      #pragma unroll
      for (int r = 0; r < 4; ++r) {
        int row = rowBase + wRow + m * 16 + r0 + r;
        if (row < M) {
          float v = sigf(acc[m][n][r] + bb);
          float sc = rowscale ? rowscale[row] : 1.0f;
          if constexpr (BF16OUT)
            ((bf16_t*)Cout)[(size_t)row * FEAT + col] = (bf16_t)(v * sc);
          else
            ((float*)Cout)[(size_t)row * FEAT + col] = v * sc;
          if (C2) C2[(size_t)row * FEAT + col] = 0.25f * v;
        }
      }
    }
  }
}

template<bool BF16OUT>
__global__ __launch_bounds__(256) void proj_mfma(
    const float* __restrict__ A, const bf16_t* __restrict__ Wt,
    const float* __restrict__ bias, void* __restrict__ Cout, int M,
    const float* __restrict__ rowscale, float* __restrict__ C2)
{
  proj_body<BF16OUT>(A, Wt, bias, Cout, M, blockIdx.x * 128, rowscale, C2);
}

// fused small projections: vmi (8 blocks), vkey (4), vval (4)
__global__ __launch_bounds__(256) void proj3_kernel(
    const float* __restrict__ x, const float* __restrict__ domain,
    const bf16_t* __restrict__ t0, const bf16_t* __restrict__ t1,
    const bf16_t* __restrict__ t2,
    const float* __restrict__ bsde, const float* __restrict__ bkey,
    const float* __restrict__ bval,
    float* __restrict__ vmi, float* __restrict__ vkey, float* __restrict__ vval)
{
  const int b = blockIdx.x;
  if (b < 8)       proj_body<false>(x, t0, bsde, vmi, BATCH, b * 128, nullptr, nullptr);
  else if (b < 12) proj_body<false>(domain, t1, bkey, vkey, ND, (b - 8) * 128, nullptr, nullptr);
  else             proj_body<false>(domain, t2, bval, vval, ND, (b - 12) * 128, nullptr, nullptr);
}

// ---------------- attention ----------------
__global__ __launch_bounds__(256) void attn_kernel(
    const float* __restrict__ vmi, const float* __restrict__ vkey,
    const float* __restrict__ vval, bf16_t* __restrict__ zm)
{
  const int i = blockIdx.x;
  const int tid = threadIdx.x;
  __shared__ float vs[FEAT];
  __shared__ float al[ND];
  __shared__ float red[4];
  __shared__ float totS;
  if (tid < FEAT) vs[tid] = vmi[(size_t)i * FEAT + tid];
  __syncthreads();
  float part = 0.f;
  for (int j = tid; j < ND; j += 256) {
    const float* kr = vkey + (size_t)j * FEAT;
    float dot = 0.f;
    #pragma unroll 8
    for (int k = 0; k < FEAT; k += 4) {
      float4 kv = *(const float4*)(kr + k);
      dot += vs[k] * kv.x + vs[k + 1] * kv.y + vs[k + 2] * kv.z + vs[k + 3] * kv.w;
    }
    al[j] = dot;
    part += dot;
  }
  #pragma unroll
  for (int o = 32; o > 0; o >>= 1) part += __shfl_down(part, o, 64);
  if ((tid & 63) == 0) red[tid >> 6] = part;
  __syncthreads();
  if (tid == 0) totS = red[0] + red[1] + red[2] + red[3];
  __syncthreads();
  const float inv = 1.0f / totS;
  if (tid < FEAT) {
    float s = 0.f;
    #pragma unroll 4
    for (int j = 0; j < ND; ++j) s += al[j] * vval[(size_t)j * FEAT + tid];
    float z = 0.5f * (s * inv + vs[tid]);
    zm[(size_t)i * FEAT + tid] = (bf16_t)z;
  }
}

// ---------------- row-gather: sum n bf16 rows of ELL list (dword per lane) ----
__device__ __forceinline__ void gatherE(const uint32_t* __restrict__ base,
                                        const u16* __restrict__ row, int n,
                                        float& ax, float& ay)
{
  float lax = 0.f, lay = 0.f;
  int j = 0;
  while (j + 8 <= n) {
    int u[8];
    #pragma unroll
    for (int q = 0; q < 8; ++q) u[q] = row[j + q];
    uint32_t w[8];
    #pragma unroll
    for (int q = 0; q < 8; ++q) w[q] = base[(size_t)u[q] * 64];
    #pragma unroll
    for (int q = 0; q < 8; ++q) {
      lax += __uint_as_float(w[q] << 16);
      lay += __uint_as_float(w[q] & 0xffff0000u);
    }
    j += 8;
  }
  while (j < n) {
    int u = row[j];
    uint32_t w = base[(size_t)u * 64];
    lax += __uint_as_float(w << 16);
    lay += __uint_as_float(w & 0xffff0000u);
    ++j;
  }
  ax = lax; ay = lay;
}

// ---- pass1 (api side): y01a = y0a + dinv_a^2 * sum_{m in N(a)} M0y[m] --------
__global__ __launch_bounds__(256) void prop_pass1(
    const bf16_t* __restrict__ M0y, const bf16_t* __restrict__ y0a,
    bf16_t* __restrict__ y01a,
    const u16* __restrict__ adja, const int* __restrict__ cnt_a,
    const float* __restrict__ da)
{
  const int a = blockIdx.x * 4 + (threadIdx.x >> 6);
  const int lane = threadIdx.x & 63;
  int n = cnt_a[a]; if (n > MD) n = MD;
  float ax, ay;
  gatherE((const uint32_t*)M0y + lane, adja + (size_t)a * MD, n, ax, ay);
  const float d = da[a];
  const float s2 = d * d;
  uint32_t y0 = ((const uint32_t*)y0a)[(size_t)a * 64 + lane];
  bf16x2 pk;
  pk[0] = (bf16_t)(__uint_as_float(y0 << 16) + s2 * ax);
  pk[1] = (bf16_t)(__uint_as_float(y0 & 0xffff0000u) + s2 * ay);
  *(bf16x2*)(y01a + (size_t)a * FEAT + 2 * lane) = pk;
}

// ---- pass2 (mashup side): Sy = M0y + dinv_m^2 * sum_{a in N(m)} y01a[a] ------
__global__ __launch_bounds__(256) void prop_pass2(
    const bf16_t* __restrict__ y01a, const bf16_t* __restrict__ M0y,
    bf16_t* __restrict__ Sy,
    const u16* __restrict__ adjm, const int* __restrict__ cnt_m,
    const float* __restrict__ dm)
{
  const int m = blockIdx.x * 4 + (threadIdx.x >> 6);
  const int lane = threadIdx.x & 63;
  int n = cnt_m[m]; if (n > MD) n = MD;
  float ax, ay;
  gatherE((const uint32_t*)y01a + lane, adjm + (size_t)m * MD, n, ax, ay);
  const float d = dm[m];
  const float s2 = d * d;
  uint32_t m0 = ((const uint32_t*)M0y)[(size_t)m * 64 + lane];
  bf16x2 pk;
  pk[0] = (bf16_t)(__uint_as_float(m0 << 16) + s2 * ax);
  pk[1] = (bf16_t)(__uint_as_float(m0 & 0xffff0000u) + s2 * ay);
  *(bf16x2*)(Sy + (size_t)m * FEAT + 2 * lane) = pk;
}

// ---- pass3 (api side): O = 0.25*A0 + 0.25*dinv_a * sum_{m in N(a)} Sy[m] -----
__global__ __launch_bounds__(256) void prop_pass3(
    const bf16_t* __restrict__ Sy, const float* __restrict__ outA,
    bf16_t* __restrict__ Obf,
    const u16* __restrict__ adja, const int* __restrict__ cnt_a,
    const float* __restrict__ da)
{
  const int a = blockIdx.x * 4 + (threadIdx.x >> 6);
  const int lane = threadIdx.x & 63;
  int n = cnt_a[a]; if (n > MD) n = MD;
  float ax, ay;
  gatherE((const uint32_t*)Sy + lane, adja + (size_t)a * MD, n, ax, ay);
  const float q = 0.25f * da[a];
  const float2 prev = *(const float2*)(outA + (size_t)a * FEAT + 2 * lane);
  bf16x2 pk;
  pk[0] = (bf16_t)(prev.x + q * ax);
  pk[1] = (bf16_t)(prev.y + q * ay);
  *(bf16x2*)(Obf + (size_t)a * FEAT + 2 * lane) = pk;
}

// ---------------- pred = Z[1024,128] @ O[50000,128]^T, bf16 MFMA --------------
__global__ __launch_bounds__(256) void pred_mfma(
    const bf16_t* __restrict__ Z, const bf16_t* __restrict__ O,
    float* __restrict__ out)
{
  const int lane = threadIdx.x & 63;
  const int wid = threadIdx.x >> 6;
  const int nBase = blockIdx.x * 256 + wid * 64;
  const int cc = lane & 15;
  const int kOff = (lane >> 4) * 8;

  bf16x8 b[4][4];
  #pragma unroll
  for (int n = 0; n < 4; ++n) {
    int c = nBase + n * 16 + cc;
    if (c > NA - 1) c = NA - 1;
    #pragma unroll
    for (int kk = 0; kk < 4; ++kk)
      b[n][kk] = *(const bf16x8*)(O + (size_t)c * FEAT + kk * 32 + kOff);
  }

  const int r0 = (lane >> 4) * 4;
  #pragma unroll
  for (int it = 0; it < 4; ++it) {
    const int iBase = blockIdx.y * 256 + it * 64;
    f32x4 acc[4][4];
    #pragma unroll
    for (int m = 0; m < 4; ++m)
      #pragma unroll
      for (int n = 0; n < 4; ++n)
        acc[m][n] = (f32x4){0.f, 0.f, 0.f, 0.f};

    #pragma unroll
    for (int kk = 0; kk < 4; ++kk) {
      bf16x8 a[4];
      #pragma unroll
      for (int m = 0; m < 4; ++m)
        a[m] = *(const bf16x8*)(Z + (size_t)(iBase + cc + m * 16) * FEAT + kk * 32 + kOff);
      #pragma unroll
      for (int m = 0; m < 4; ++m)
        #pragma unroll
        for (int n = 0; n < 4; ++n)
          acc[m][n] = __builtin_amdgcn_mfma_f32_16x16x32_bf16(a[m], b[n][kk], acc[m][n], 0, 0, 0);
    }

    #pragma unroll
    for (int n = 0; n < 4; ++n) {
      int col = nBase + n * 16 + cc;
      if (col < NA) {
        #pragma unroll
        for (int m = 0; m < 4; ++m) {
          #pragma unroll
          for (int r = 0; r < 4; ++r) {
            int row = iBase + m * 16 + r0 + r;
            __builtin_nontemporal_store(acc[m][n][r], &out[(size_t)row * NA + col]);
          }
        }
      }
    }
  }
}

static inline char* alignup(char* p, size_t a) {
  return (char*)(((uintptr_t)p + a - 1) & ~(uintptr_t)(a - 1));
}

extern "C" void kernel_launch(void* const* d_in, const int* in_sizes, int n_in,
                              void* d_out, int out_size, void* d_ws, size_t ws_size,
                              hipStream_t stream) {
  const float* x      = (const float*)d_in[0];
  const float* mashup = (const float*)d_in[1];
  const float* domain = (const float*)d_in[2];
  const float* api    = (const float*)d_in[3];
  const float* Wsde   = (const float*)d_in[4];
  const float* bsde   = (const float*)d_in[5];
  const float* Wval   = (const float*)d_in[6];
  const float* bval   = (const float*)d_in[7];
  const float* Wkey   = (const float*)d_in[8];
  const float* bkey   = (const float*)d_in[9];
  const float* Wsie   = (const float*)d_in[10];
  const float* bsie   = (const float*)d_in[11];
  const int* esrc     = (const int*)d_in[12];
  const int* edst     = (const int*)d_in[13];
  float* out = (float*)d_out;

  // workspace layout (~118 MB)
  char* p = (char*)d_ws;
  bf16_t* M0y  = (bf16_t*)p; p += (size_t)NM * FEAT * 2;          // 12.8MB
  bf16_t* y0a  = (bf16_t*)p; p += (size_t)NA * FEAT * 2;          // 12.8MB
  bf16_t* y01a = (bf16_t*)p; p += (size_t)NA * FEAT * 2;          // 12.8MB
  bf16_t* Sy   = (bf16_t*)p; p += (size_t)NM * FEAT * 2;          // 12.8MB
  float*  outA = (float*)p;  p += (size_t)NA * FEAT * 4;          // 25.6MB
  bf16_t* Obf  = (bf16_t*)p; p += (size_t)NA * FEAT * 2;          // 12.8MB
  u16*    adjm = (u16*)p;    p += (size_t)NM * MD * 2;            // 12.8MB
  u16*    adja = (u16*)p;    p += (size_t)NA * MD * 2;            // 12.8MB
  float*  vmi  = (float*)p;  p += (size_t)BATCH * FEAT * 4;
  float*  vkey = (float*)p;  p += (size_t)ND * FEAT * 4;
  float*  vval = (float*)p;  p += (size_t)ND * FEAT * 4;
  bf16_t* zm   = (bf16_t*)p; p += (size_t)BATCH * FEAT * 2;
  int* cnt_m = (int*)p; p += (size_t)NM * 4;                      // contiguous with
  int* cnt_a = (int*)p; p += (size_t)NA * 4;                      // cnt_m (one memset)
  float* dm  = (float*)p; p += (size_t)NM * 4;
  float* da  = (float*)p; p += (size_t)NA * 4;
  p = alignup(p, 16);
  bf16_t* wt0 = (bf16_t*)p; p += (size_t)FEAT * KDIM * 2;
  bf16_t* wt1 = (bf16_t*)p; p += (size_t)FEAT * KDIM * 2;
  bf16_t* wt2 = (bf16_t*)p; p += (size_t)FEAT * KDIM * 2;
  bf16_t* wt3 = (bf16_t*)p; p += (size_t)FEAT * KDIM * 2;

  hipMemsetAsync(cnt_m, 0, (size_t)(NM + NA) * sizeof(int), stream);

  // ---- build (ELL, rank trick: no hist, no scans) ----
  fill_ell<<<2048, 256, 0, stream>>>(esrc, edst, cnt_m, cnt_a, adjm, adja);
  util_kernel<<<512 + (NM + 255) / 256, 256, 0, stream>>>(
      Wsde, Wkey, Wval, Wsie, wt0, wt1, wt2, wt3, cnt_m, cnt_a, dm, da);

  // ---- projections ----
  proj3_kernel<<<16, 256, 0, stream>>>(x, domain, wt0, wt1, wt2,
                                       bsde, bkey, bval, vmi, vkey, vval);
  attn_kernel<<<BATCH, 256, 0, stream>>>(vmi, vkey, vval, zm);

  // mashup: M0y = dm[m]*sigmoid(...); api: y0a = da[a]*sigmoid(...), outA = 0.25*sig
  proj_mfma<true><<<(NM + 127) / 128, 256, 0, stream>>>(mashup, wt0, bsde, M0y, NM,
                                                        dm, nullptr);
  proj_mfma<true><<<(NA + 127) / 128, 256, 0, stream>>>(api, wt3, bsie, y0a, NA,
                                                        da, outA);

  // ---- bipartite LightGCN: out_api = 0.25*(A0 + P^T(M0+M1+M2)) ----
  prop_pass1<<<NA / 4, 256, 0, stream>>>(M0y, y0a, y01a, adja, cnt_a, da);
  prop_pass2<<<NM / 4, 256, 0, stream>>>(y01a, M0y, Sy, adjm, cnt_m, dm);
  prop_pass3<<<NA / 4, 256, 0, stream>>>(Sy, outA, Obf, adja, cnt_a, da);

  pred_mfma<<<dim3((NA + 255) / 256, BATCH / 256), 256, 0, stream>>>(zm, Obf, out);
}